// Round 5
// baseline (755.163 us; speedup 1.0000x reference)
//
#include <hip/hip_runtime.h>

// DeepSeek-V2 expert MLP, fp8-block-dequant weights. T=8192, H=5120, F=1536.
// Pipeline (3 dispatches):
//   1) prep: x f32->bf16; wg,wu dequant->bf16 INTERLEAVED into wq[3072][5120];
//      wd dequant->bf16 wdq[5120][1536].  (unchanged, verified)
//   2) gemm_p<FUSE_SILU>: h = silu/up-pair epilogue of xb @ wq^T.
//   3) gemm_p<plain>: out = h @ wdq^T, f32.
// GEMM round-5: R4 skeleton (tile 128x256, 256 thr = 4 waves, per-wave
// 128x64, ring-3 LDS 72 KB => 2 blocks/CU, 2 phases/kslice, counted VMBAR(6))
// with the compute core swapped to v_mfma_f32_32x32x16_bf16 (2495 TF ubench
// ceiling vs 2075 for 16x16x32; half the MFMA instrs and A-frag reads).
// Adaptations: swizzle bits moved to (byte4^=row1, byte5^=row2) since 32-row
// frags read 16 rows at one 16B column (2 lanes/bank = free); C/D layout =
// m74/m101-verified col=lane&31, row=(reg&3)+8*(reg>>2)+4*(lane>>5).
// Kept verified: linear glds dest + inverse-swizzled global src (rule #21),
// setprio [T5], bijective XCD chunk swizzle [T1] (grids 768/1280, %8==0).

typedef __bf16 bf16x8 __attribute__((ext_vector_type(8)));
typedef float  f32x4  __attribute__((ext_vector_type(4)));
typedef float  f32x16 __attribute__((ext_vector_type(16)));

__device__ __forceinline__ void glds16(const __bf16* g, __bf16* l) {
  __builtin_amdgcn_global_load_lds(
      (const __attribute__((address_space(1))) void*)g,
      (__attribute__((address_space(3))) void*)l, 16, 0, 0);
}

// Inverse of the read-side swizzle: for linear 16B LDS chunk c of a region,
// which logical (row, k) must be fetched there. Subtile = 16 rows x 32 bf16
// = 1024 B; storage byte = logical ^ ((row&2)<<3) ^ ((row&4)<<3), i.e.
// byte4 ^= row bit1 (=byte bit7), byte5 ^= row bit2 (=byte bit8).
__device__ __forceinline__ void chunk_rk(int c, int& row, int& k) {
  int s = c >> 6;                 // subtile index (16 rows each)
  int w = (c & 63) << 4;          // storage byte within subtile
  int wl = w ^ (((w >> 7) & 1) << 4) ^ (((w >> 8) & 1) << 5);
  row = (s << 4) + (wl >> 6);
  k = (wl & 63) >> 1;
}

#define BAR()                               \
  do {                                      \
    __builtin_amdgcn_sched_barrier(0);      \
    asm volatile("s_barrier" ::: "memory"); \
    __builtin_amdgcn_sched_barrier(0);      \
  } while (0)

#define LGKM0()                                        \
  do {                                                 \
    asm volatile("s_waitcnt lgkmcnt(0)" ::: "memory"); \
    __builtin_amdgcn_sched_barrier(0);                 \
  } while (0)

#define VMBAR(n)                                                       \
  do {                                                                 \
    __builtin_amdgcn_sched_barrier(0);                                 \
    asm volatile("s_waitcnt vmcnt(" #n ")\n\ts_barrier" ::: "memory"); \
    __builtin_amdgcn_sched_barrier(0);                                 \
  } while (0)

// ---- fused prep: xcast + 3 dequants in one launch (unchanged) -------------
__device__ __forceinline__ void cast8(const float* __restrict__ in,
                                      __bf16* __restrict__ out, size_t idx) {
  f32x4 a = *(const f32x4*)(in + idx);
  f32x4 b = *(const f32x4*)(in + idx + 4);
  bf16x8 o;
#pragma unroll
  for (int i = 0; i < 4; ++i) { o[i] = (__bf16)a[i]; o[i + 4] = (__bf16)b[i]; }
  *(bf16x8*)(out + idx) = o;
}

__device__ __forceinline__ void dq_ilv(const float* __restrict__ w,
                                       const float* __restrict__ s,
                                       __bf16* __restrict__ wq, int r, int tid,
                                       int which) {
  unsigned idx = ((unsigned)r * 256u + (unsigned)tid) * 8u;
  unsigned f = idx / 5120u;
  unsigned h = idx - f * 5120u;
  float sc = s[(f >> 7) * 40 + (h >> 7)];
  f32x4 a = *(const f32x4*)(w + idx);
  f32x4 b = *(const f32x4*)(w + idx + 4);
  bf16x8 o;
#pragma unroll
  for (int i = 0; i < 4; ++i) {
    o[i] = (__bf16)(a[i] * sc);
    o[i + 4] = (__bf16)(b[i] * sc);
  }
  *(bf16x8*)(wq + (size_t)(2 * f + which) * 5120 + h) = o;
}

__device__ __forceinline__ void dq_wd(const float* __restrict__ w,
                                      const float* __restrict__ s,
                                      __bf16* __restrict__ o8, int r, int tid) {
  unsigned idx = ((unsigned)r * 256u + (unsigned)tid) * 8u;
  unsigned f = idx / 1536u;
  unsigned h = idx - f * 1536u;
  float sc = s[(f >> 7) * 12 + (h >> 7)];
  f32x4 a = *(const f32x4*)(w + idx);
  f32x4 b = *(const f32x4*)(w + idx + 4);
  bf16x8 o;
#pragma unroll
  for (int i = 0; i < 4; ++i) {
    o[i] = (__bf16)(a[i] * sc);
    o[i + 4] = (__bf16)(b[i] * sc);
  }
  *(bf16x8*)(o8 + idx) = o;
}

__global__ void prep(const float* __restrict__ x, const float* __restrict__ wg,
                     const float* __restrict__ sg, const float* __restrict__ wu,
                     const float* __restrict__ su, const float* __restrict__ wd,
                     const float* __restrict__ sd, __bf16* __restrict__ xb,
                     __bf16* __restrict__ wq, __bf16* __restrict__ wdq) {
  int bid = blockIdx.x;
  int tid = threadIdx.x;
  if (bid < 20480) {
    cast8(x, xb, ((size_t)bid * 256 + tid) * 8);
  } else if (bid < 24320) {
    dq_ilv(wg, sg, wq, bid - 20480, tid, 0);
  } else if (bid < 28160) {
    dq_ilv(wu, su, wq, bid - 24320, tid, 1);
  } else {
    dq_wd(wd, sd, wdq, bid - 28160, tid);
  }
}

// ---- pipelined GEMM: C = A @ B^T ------------------------------------------
// A:[M,K] bf16, B:[N,K] bf16. Tile 128(M) x 256(N), 4 waves, kslice ring-3.
// Wave w owns N-stripe w*64 (2 x 32-col frags), full 128 M rows (4 x 32-row
// frags). acc[4][2] of f32x16. 16 x 32x32x16 MFMA per kslice.
template <bool FUSE_SILU, typename OutT>
__global__ __launch_bounds__(256, 2) void gemm_p(
    const __bf16* __restrict__ A, const __bf16* __restrict__ B,
    OutT* __restrict__ C, int M, int N, int K, int ldc, int nbx) {
  __shared__ __bf16 lds[3 * 12288];  // slot = A 4096 + B 8192 bf16 = 24 KB
  const int tid = threadIdx.x;
  const int lane = tid & 63;
  const int wave = tid >> 6;   // 0..3 = N-wave (each wave: 128 x 64 output)

  // bijective XCD-chunked swizzle (gridDim.x % 8 == 0 by construction)
  const int nwg = gridDim.x;
  const int lb = (blockIdx.x & 7) * (nwg >> 3) + (blockIdx.x >> 3);
  const int bx = lb % nbx;
  const int by = lb / nbx;
  const int m0 = by * 128, n0 = bx * 256;

  // 32x32x16 A/B fragment addressing within a region of [rows][32 K] 1KB
  // subtiles: logical byte = (row>>4)*1024 + (row&15)*64 + kk*32 +
  // (lane>>5)*16, row = frag_base + (lane&31); storage XOR: byte4^=row1,
  // byte5^=row2 (row bits 1,2 == lane bits 1,2).
  const int hio = (((lane & 31) >> 4) << 10) | ((lane & 15) << 6);
  const int swz = ((lane & 2) << 3) | ((lane & 4) << 3);
  const int ko0 = (((lane >> 5) << 4) | 0) ^ swz;   // kk = 0
  const int ko1 = (((lane >> 5) << 4) | 32) ^ swz;  // kk = 1

  // staging: per kslice each thread: A chunks {tid, tid+256} (8 KB total),
  // B chunks {tid, tid+256, tid+512, tid+768} (16 KB total); inverse-swizzled
  // global source, linear LDS destination.
  int rr[4], kk[4];
  chunk_rk(tid, rr[0], kk[0]);
  chunk_rk(tid + 256, rr[1], kk[1]);
  chunk_rk(tid + 512, rr[2], kk[2]);
  chunk_rk(tid + 768, rr[3], kk[3]);
  const unsigned o0 = (unsigned)rr[0] * K + (unsigned)kk[0];
  const unsigned o1 = (unsigned)rr[1] * K + (unsigned)kk[1];
  const unsigned o2 = (unsigned)rr[2] * K + (unsigned)kk[2];
  const unsigned o3 = (unsigned)rr[3] * K + (unsigned)kk[3];
  const int d0 = tid << 3, d1 = (tid + 256) << 3;
  const int d2 = (tid + 512) << 3, d3 = (tid + 768) << 3;
  const __bf16* Ab = A + (size_t)m0 * K;
  const __bf16* Bb = B + (size_t)n0 * K;

  f32x16 acc[4][2] = {};
  bf16x8 af[4], bg[2];

  auto STAGE_P0 = [&](int t, int s) {  // A (2 loads) + B lower half (2)
    __bf16* sb = lds + s * 12288;
    const unsigned ko = (unsigned)t << 5;
    glds16(Ab + (o0 + ko), sb + d0);
    glds16(Ab + (o1 + ko), sb + d1);
    glds16(Bb + (o0 + ko), sb + 4096 + d0);
    glds16(Bb + (o1 + ko), sb + 4096 + d1);
  };
  auto STAGE_P1 = [&](int t, int s) {  // B upper half (2 loads)
    __bf16* sb = lds + s * 12288;
    const unsigned ko = (unsigned)t << 5;
    glds16(Bb + (o2 + ko), sb + 4096 + d2);
    glds16(Bb + (o3 + ko), sb + 4096 + d3);
  };
  auto RD = [&](const char* cb, int ko) {
#pragma unroll
    for (int i = 0; i < 4; ++i)
      af[i] = *(const bf16x8*)(cb + i * 2048 + hio + ko);
#pragma unroll
    for (int j = 0; j < 2; ++j)
      bg[j] = *(const bf16x8*)(cb + 8192 + (wave << 12) + j * 2048 + hio + ko);
  };
  auto MFMA8 = [&] {
    __builtin_amdgcn_s_setprio(1);
#pragma unroll
    for (int j = 0; j < 2; ++j)
#pragma unroll
      for (int i = 0; i < 4; ++i)
        acc[i][j] = __builtin_amdgcn_mfma_f32_32x32x16_bf16(af[i], bg[j],
                                                            acc[i][j], 0, 0, 0);
    __builtin_amdgcn_s_setprio(0);
  };

  const int NT = K >> 5;  // 160 (gemm1) / 48 (gemm2)

  // prologue: stage kslices 0,1 (12 loads); wait oldest 6 (slice 0 ready)
  STAGE_P0(0, 0);
  STAGE_P1(0, 0);
  STAGE_P0(1, 1);
  STAGE_P1(1, 1);
  VMBAR(6);

  int cur = 0, stg = 2;
  for (int t = 0; t < NT - 2; ++t) {
    const char* cb = (const char*)lds + cur * 24576;
    RD(cb, ko0);
    STAGE_P0(t + 2, stg);
    BAR();
    LGKM0();
    MFMA8();
    BAR();
    RD(cb, ko1);
    STAGE_P1(t + 2, stg);
    BAR();
    LGKM0();
    MFMA8();
    VMBAR(6);  // slice t+1 fully staged; slice t+2's 6 loads stay in flight
    cur = (cur == 2) ? 0 : cur + 1;
    stg = (stg == 2) ? 0 : stg + 1;
  }
  {  // t = NT-2: no staging; drain to 0 so slice NT-1 is readable
    const char* cb = (const char*)lds + cur * 24576;
    RD(cb, ko0);
    BAR();
    LGKM0();
    MFMA8();
    BAR();
    RD(cb, ko1);
    BAR();
    LGKM0();
    MFMA8();
    VMBAR(0);
    cur = (cur == 2) ? 0 : cur + 1;
  }
  {  // t = NT-1: last slice
    const char* cb = (const char*)lds + cur * 24576;
    RD(cb, ko0);
    LGKM0();
    MFMA8();
    RD(cb, ko1);
    LGKM0();
    MFMA8();
  }

  // C/D layout for 32x32 (m74/m101-verified):
  // col = lane&31, row = (reg&3) + 8*(reg>>2) + 4*(lane>>5).
  const int colx = n0 + (wave << 6) + (lane & 31);
  const int rbase = m0 + ((lane >> 5) << 2);
#pragma unroll
  for (int i = 0; i < 4; ++i)
#pragma unroll
    for (int j = 0; j < 2; ++j)
#pragma unroll
      for (int r = 0; r < 16; ++r) {
        const int row = rbase + i * 32 + (r & 3) + ((r >> 2) << 3);
        const int col = colx + j * 32;
        if constexpr (FUSE_SILU) {
          // lanes (2k,2k+1) hold cols (gate_f, up_f) of the same row.
          float v = acc[i][j][r];
          float p = __shfl_xor(v, 1, 64);
          float g = (lane & 1) ? p : v;
          float u = (lane & 1) ? v : p;
          float hv = (g / (1.0f + __expf(-g))) * u;
          if ((lane & 1) == 0)
            C[(size_t)row * ldc + (col >> 1)] = (OutT)hv;
        } else {
          C[(size_t)row * ldc + col] = (OutT)acc[i][j][r];
        }
      }
}

extern "C" void kernel_launch(void* const* d_in, const int* in_sizes, int n_in,
                              void* d_out, int out_size, void* d_ws,
                              size_t ws_size, hipStream_t stream) {
  const int Hd = 5120, Fd = 1536, Td = 8192;
  const float* x = (const float*)d_in[0];
  const float* wg = (const float*)d_in[1];
  const float* sg = (const float*)d_in[2];
  const float* wu = (const float*)d_in[3];
  const float* su = (const float*)d_in[4];
  const float* wd = (const float*)d_in[5];
  const float* sd = (const float*)d_in[6];
  float* out = (float*)d_out;

  // ws layout (bf16): xb [T*H] | wq [2F*H] | wdq [H*F] | h [T*F]  ~156 MB
  __bf16* ws = (__bf16*)d_ws;
  const size_t xsz = (size_t)Td * Hd;
  __bf16* xb = ws;
  __bf16* wq = xb + xsz;
  __bf16* wdq = wq + (size_t)2 * Fd * Hd;
  __bf16* hbuf = wdq + (size_t)Hd * Fd;

  prep<<<32000, 256, 0, stream>>>(x, wg, sg, wu, su, wd, sd, xb, wq, wdq);

  // gemm1: [8192 x 3072] = xb @ wq^T, silu-pair epilogue -> h [8192][1536]
  // grid = (8192/128) * (3072/256) = 64 * 12 = 768 (%8==0); 2 blk/CU
  gemm_p<true, __bf16><<<768, 256, 0, stream>>>(xb, wq, hbuf, Td, 2 * Fd, Hd,
                                                Fd, 12);

  // gemm2: [8192 x 5120] = h @ wdq^T -> out f32
  // grid = 64 * 20 = 1280 (%8==0); 2 blk/CU
  gemm_p<false, float><<<1280, 256, 0, stream>>>(hbuf, wdq, out, Td, Hd, Fd,
                                                 Hd, 20);
}